// Round 1
// baseline (782.058 us; speedup 1.0000x reference)
//
#include <hip/hip_runtime.h>
#include <cstdint>

#define B_ 4
#define L_ 4096
#define D_ 256
#define DI_ 512
#define DS_ 16
#define DR_ 16
#define NC_ 64
#define CL_ 64
#define KS_ 8
#define EPS_ 1e-5f
#define SCALE_ 0.0625f

// ---------------- generic fp32 tiled GEMM: C = A(MxK) * B(KxN) (+bias) ------
// requirements: M % 64 == 0, K % 16 == 0. N guarded. batch via blockIdx.z.
#define FMA16(a4, b4, acc) do { \
  acc[0][0] = fmaf(a4.x, b4.x, acc[0][0]); \
  acc[0][1] = fmaf(a4.x, b4.y, acc[0][1]); \
  acc[0][2] = fmaf(a4.x, b4.z, acc[0][2]); \
  acc[0][3] = fmaf(a4.x, b4.w, acc[0][3]); \
  acc[1][0] = fmaf(a4.y, b4.x, acc[1][0]); \
  acc[1][1] = fmaf(a4.y, b4.y, acc[1][1]); \
  acc[1][2] = fmaf(a4.y, b4.z, acc[1][2]); \
  acc[1][3] = fmaf(a4.y, b4.w, acc[1][3]); \
  acc[2][0] = fmaf(a4.z, b4.x, acc[2][0]); \
  acc[2][1] = fmaf(a4.z, b4.y, acc[2][1]); \
  acc[2][2] = fmaf(a4.z, b4.z, acc[2][2]); \
  acc[2][3] = fmaf(a4.z, b4.w, acc[2][3]); \
  acc[3][0] = fmaf(a4.w, b4.x, acc[3][0]); \
  acc[3][1] = fmaf(a4.w, b4.y, acc[3][1]); \
  acc[3][2] = fmaf(a4.w, b4.z, acc[3][2]); \
  acc[3][3] = fmaf(a4.w, b4.w, acc[3][3]); \
} while (0)

__global__ __launch_bounds__(256) void gemm_rrr(
    const float* __restrict__ A, int lda, long sA,
    const float* __restrict__ Bm, int ldb, long sB,
    float* __restrict__ C, int ldc, long sC,
    const float* __restrict__ bias, int M, int N, int K)
{
  __shared__ float As[16][68];  // [k][m], padded row
  __shared__ float Bs[16][68];  // [k][n]
  const int t = threadIdx.x;
  const int tx = t & 15, ty = t >> 4;
  const int m0 = blockIdx.y * 64, n0 = blockIdx.x * 64;
  const float* Ab = A + (long)blockIdx.z * sA;
  const float* Bb = Bm + (long)blockIdx.z * sB;
  float* Cb = C + (long)blockIdx.z * sC;
  const int am = t >> 2, ak = (t & 3) << 2;   // A: row m0+am, cols k0+ak..+3
  const int bk = t >> 4, bn = (t & 15) << 2;  // B: row k0+bk, cols n0+bn..+3
  float acc[4][4] = {};
  for (int k0 = 0; k0 < K; k0 += 16) {
    float4 av = *(const float4*)(Ab + (long)(m0 + am) * lda + k0 + ak);
    float4 bv = make_float4(0.f, 0.f, 0.f, 0.f);
    if (n0 + bn < N) {
      if (n0 + bn + 3 < N) {
        bv = *(const float4*)(Bb + (long)(k0 + bk) * ldb + n0 + bn);
      } else {
        const float* p = Bb + (long)(k0 + bk) * ldb + n0 + bn;
        int rem = N - (n0 + bn);
        bv.x = p[0];
        if (rem > 1) bv.y = p[1];
        if (rem > 2) bv.z = p[2];
      }
    }
    __syncthreads();
    As[ak + 0][am] = av.x;
    As[ak + 1][am] = av.y;
    As[ak + 2][am] = av.z;
    As[ak + 3][am] = av.w;
    *(float4*)&Bs[bk][bn] = bv;
    __syncthreads();
#pragma unroll
    for (int kk = 0; kk < 16; ++kk) {
      float4 a4 = *(const float4*)&As[kk][ty << 2];
      float4 b4 = *(const float4*)&Bs[kk][tx << 2];
      FMA16(a4, b4, acc);
    }
  }
#pragma unroll
  for (int i = 0; i < 4; ++i) {
    int row = m0 + (ty << 2) + i;
    int col0 = n0 + (tx << 2);
    float* cp = Cb + (long)row * ldc + col0;
    if (col0 + 3 < N) {
      float4 cv;
      cv.x = acc[i][0]; cv.y = acc[i][1]; cv.z = acc[i][2]; cv.w = acc[i][3];
      if (bias) { cv.x += bias[col0]; cv.y += bias[col0+1]; cv.z += bias[col0+2]; cv.w += bias[col0+3]; }
      *(float4*)cp = cv;
    } else {
#pragma unroll
      for (int j = 0; j < 4; ++j) {
        int col = col0 + j;
        if (col < N) cp[j] = acc[i][j] + (bias ? bias[col] : 0.f);
      }
    }
  }
}

// ---------------- sim = k^T v (split-K partials) ----------------------------
// kv layout: (B, L, 512) rows = [k(256) | v(256)]. part[ks][b][m][n].
__global__ __launch_bounds__(256) void sim_k(const float* __restrict__ kv, float* __restrict__ part)
{
  __shared__ float As[16][68];
  __shared__ float Bs[16][68];
  const int t = threadIdx.x;
  const int tx = t & 15, ty = t >> 4;
  const int m0 = blockIdx.y * 64, n0 = blockIdx.x * 64;
  const int b = blockIdx.z >> 3, ks = blockIdx.z & 7;
  const float* base = kv + (long)b * L_ * 512;
  const int k0s = ks * (L_ / KS_);
  const int bk = t >> 4, bn = (t & 15) << 2;
  float acc[4][4] = {};
  for (int k0 = k0s; k0 < k0s + L_ / KS_; k0 += 16) {
    const float* rp = base + (long)(k0 + bk) * 512;
    float4 av = *(const float4*)(rp + m0 + bn);
    float4 bv = *(const float4*)(rp + 256 + n0 + bn);
    __syncthreads();
    *(float4*)&As[bk][bn] = av;
    *(float4*)&Bs[bk][bn] = bv;
    __syncthreads();
#pragma unroll
    for (int kk = 0; kk < 16; ++kk) {
      float4 a4 = *(const float4*)&As[kk][ty << 2];
      float4 b4 = *(const float4*)&Bs[kk][tx << 2];
      FMA16(a4, b4, acc);
    }
  }
  float* pp = part + ((long)(ks * B_ + b) * 256) * 256;
#pragma unroll
  for (int i = 0; i < 4; ++i) {
    float4 cv;
    cv.x = acc[i][0]; cv.y = acc[i][1]; cv.z = acc[i][2]; cv.w = acc[i][3];
    *(float4*)(pp + (long)(m0 + (ty << 2) + i) * 256 + n0 + (tx << 2)) = cv;
  }
}

// ---------------- softmax over e (reduces split-K partials) -----------------
__global__ __launch_bounds__(256) void softmax_k(const float* __restrict__ part, float* __restrict__ attn)
{
  __shared__ float red[8];
  const int b = blockIdx.x >> 8;
  const int row = blockIdx.x & 255;
  const int e = threadIdx.x;
  float s = 0.f;
#pragma unroll
  for (int ks = 0; ks < KS_; ++ks)
    s += part[(((long)ks * B_ + b) * 256 + row) * 256 + e];
  s *= SCALE_;
  const int lane = e & 63, wid = e >> 6;
  float m = s;
  for (int o = 32; o; o >>= 1) m = fmaxf(m, __shfl_down(m, o, 64));
  if (!lane) red[wid] = m;
  __syncthreads();
  if (e == 0) red[0] = fmaxf(fmaxf(red[0], red[1]), fmaxf(red[2], red[3]));
  __syncthreads();
  m = red[0];
  __syncthreads();
  float p = expf(s - m);
  float su = p;
  for (int o = 32; o; o >>= 1) su += __shfl_down(su, o, 64);
  if (!lane) red[wid] = su;
  __syncthreads();
  if (e == 0) red[0] = red[0] + red[1] + red[2] + red[3];
  __syncthreads();
  su = red[0];
  attn[((long)b * 256 + row) * 256 + e] = p / su;
}

// ---------------- LayerNorm(2*ob) in-place ----------------------------------
__global__ __launch_bounds__(256) void ln_k(float* __restrict__ ob, const float* __restrict__ w, const float* __restrict__ bb)
{
  __shared__ float red[8];
  const long base = (long)blockIdx.x * 256;
  const int t = threadIdx.x;
  const int lane = t & 63, wid = t >> 6;
  float v = 2.f * ob[base + t];
  float s = v;
  for (int o = 32; o; o >>= 1) s += __shfl_down(s, o, 64);
  if (!lane) red[wid] = s;
  __syncthreads();
  if (t == 0) red[0] = red[0] + red[1] + red[2] + red[3];
  __syncthreads();
  float mean = red[0] * (1.f / 256.f);
  __syncthreads();
  float dv = v - mean;
  float s2 = dv * dv;
  for (int o = 32; o; o >>= 1) s2 += __shfl_down(s2, o, 64);
  if (!lane) red[wid] = s2;
  __syncthreads();
  if (t == 0) red[0] = red[0] + red[1] + red[2] + red[3];
  __syncthreads();
  float var = red[0] * (1.f / 256.f);
  ob[base + t] = dv * rsqrtf(var + EPS_) * w[t] + bb[t];
}

// ---------------- depthwise causal conv (DC=4) + SiLU -----------------------
__global__ __launch_bounds__(512) void conv_silu_k(const float* __restrict__ xz, const float* __restrict__ cw,
                                                   const float* __restrict__ cb, float* __restrict__ xs)
{
  const int d = threadIdx.x;
  const long row = blockIdx.x;           // b*L + l
  const int l = blockIdx.x & (L_ - 1);
  const float w0 = cw[d * 4 + 0], w1 = cw[d * 4 + 1], w2 = cw[d * 4 + 2], w3 = cw[d * 4 + 3];
  float acc = cb[d];
  if (l >= 3) {
    const float* p = xz + (row - 3) * 1024 + d;
    acc = fmaf(p[0], w0, acc);
    acc = fmaf(p[1024], w1, acc);
    acc = fmaf(p[2048], w2, acc);
    acc = fmaf(p[3072], w3, acc);
  } else {
    const float w[4] = {w0, w1, w2, w3};
#pragma unroll
    for (int j = 0; j < 4; ++j) {
      int ll = l - 3 + j;
      if (ll >= 0) acc = fmaf(xz[(row - 3 + j) * 1024 + d], w[j], acc);
    }
  }
  xs[row * 512 + d] = acc / (1.f + expf(-acc));
}

// ---------------- dt = softplus(dt_r @ dt_proj_w + b) -----------------------
__global__ __launch_bounds__(512) void dt_k(const float* __restrict__ dbl, const float* __restrict__ dtw,
                                            const float* __restrict__ dtb, float* __restrict__ dt)
{
  const int d = threadIdx.x;
  const long r = blockIdx.x;
  float acc = dtb[d];
#pragma unroll
  for (int k = 0; k < 16; ++k) acc = fmaf(dbl[r * 48 + k], dtw[k * 512 + d], acc);
  dt[r * 512 + d] = fmaxf(acc, 0.f) + log1pf(expf(-fabsf(acc)));
}

// ---------------- scan pass A: per-chunk (prod dA, local state) -------------
__global__ __launch_bounds__(512) void scanA_k(const float* __restrict__ dt, const float* __restrict__ xs,
                                               const float* __restrict__ dbl, const float* __restrict__ A_log,
                                               float* __restrict__ Pbuf, float* __restrict__ Hbuf)
{
  __shared__ float Bm_s[CL_][DS_];
  const int d = threadIdx.x;
  const int b = blockIdx.x >> 6, c = blockIdx.x & 63;
  const long l0 = (long)b * L_ + c * CL_;
#pragma unroll
  for (int i = 0; i < 2; ++i) {
    int idx = i * 512 + d;
    Bm_s[idx >> 4][idx & 15] = dbl[(l0 + (idx >> 4)) * 48 + 16 + (idx & 15)];
  }
  float A_s[16], h[16] = {}, P[16];
#pragma unroll
  for (int s = 0; s < 16; ++s) { A_s[s] = -expf(A_log[d * 16 + s]); P[s] = 1.f; }
  __syncthreads();
  for (int tt = 0; tt < CL_; ++tt) {
    long r = l0 + tt;
    float dtv = dt[r * 512 + d];
    float xv = xs[r * 512 + d];
    float du = dtv * xv;
#pragma unroll
    for (int s = 0; s < 16; ++s) {
      float a = expf(dtv * A_s[s]);
      h[s] = fmaf(a, h[s], du * Bm_s[tt][s]);
      P[s] *= a;
    }
  }
  long o = ((long)blockIdx.x * 512 + d) * 16;
#pragma unroll
  for (int s = 0; s < 16; ++s) { Pbuf[o + s] = P[s]; Hbuf[o + s] = h[s]; }
}

// ---------------- scan pass B: chunk prefix (in-place carry-in) -------------
__global__ __launch_bounds__(256) void scanB_k(const float* __restrict__ Pbuf, float* __restrict__ Hbuf)
{
  const long gid = (long)blockIdx.x * 256 + threadIdx.x;   // B*DI*DS = 131072
  const int b = (int)(gid >> 13);
  const int r = (int)(gid & 8191);
  float carry = 0.f;
  for (int c = 0; c < NC_; ++c) {
    long off = ((long)(b * NC_ + c) << 13) + r;
    float Pv = Pbuf[off];
    float Hv = Hbuf[off];
    Hbuf[off] = carry;            // state BEFORE chunk c
    carry = fmaf(Pv, carry, Hv);
  }
}

// ---------------- scan pass C: replay with carry-in, fused epilogue ---------
__global__ __launch_bounds__(512) void scanC_k(const float* __restrict__ dt, const float* __restrict__ xs,
                                               const float* __restrict__ dbl, const float* __restrict__ xz,
                                               const float* __restrict__ A_log, const float* __restrict__ Dskip,
                                               const float* __restrict__ Hbuf, float* __restrict__ y)
{
  __shared__ float Bm_s[CL_][DS_];
  __shared__ float Cm_s[CL_][DS_];
  const int d = threadIdx.x;
  const int b = blockIdx.x >> 6, c = blockIdx.x & 63;
  const long l0 = (long)b * L_ + c * CL_;
#pragma unroll
  for (int i = 0; i < 2; ++i) {
    int idx = i * 512 + d;
    int row = idx >> 4, s = idx & 15;
    Bm_s[row][s] = dbl[(l0 + row) * 48 + 16 + s];
    Cm_s[row][s] = dbl[(l0 + row) * 48 + 32 + s];
  }
  float A_s[16], h[16];
  const long o = ((long)blockIdx.x * 512 + d) * 16;
#pragma unroll
  for (int s = 0; s < 16; ++s) { A_s[s] = -expf(A_log[d * 16 + s]); h[s] = Hbuf[o + s]; }
  const float Dv = Dskip[d];
  __syncthreads();
  for (int tt = 0; tt < CL_; ++tt) {
    long r = l0 + tt;
    float dtv = dt[r * 512 + d];
    float xv = xs[r * 512 + d];
    float zv = xz[r * 1024 + 512 + d];
    float du = dtv * xv;
    float acc = 0.f;
#pragma unroll
    for (int s = 0; s < 16; ++s) {
      float a = expf(dtv * A_s[s]);
      h[s] = fmaf(a, h[s], du * Bm_s[tt][s]);
      acc = fmaf(h[s], Cm_s[tt][s], acc);
    }
    float yv = fmaf(xv, Dv, acc);
    y[r * 512 + d] = yv * (zv / (1.f + expf(-zv)));
  }
}

extern "C" void kernel_launch(void* const* d_in, const int* in_sizes, int n_in,
                              void* d_out, int out_size, void* d_ws, size_t ws_size,
                              hipStream_t stream)
{
  const float* x         = (const float*)d_in[0];
  const float* context   = (const float*)d_in[1];
  const float* Wq        = (const float*)d_in[2];
  const float* Wkv       = (const float*)d_in[3];
  const float* ln_w      = (const float*)d_in[4];
  const float* ln_b      = (const float*)d_in[5];
  const float* in_proj_w = (const float*)d_in[6];
  const float* conv_w    = (const float*)d_in[7];
  const float* conv_b    = (const float*)d_in[8];
  const float* x_proj_w  = (const float*)d_in[9];
  const float* dt_proj_w = (const float*)d_in[10];
  const float* dt_proj_b = (const float*)d_in[11];
  const float* A_log     = (const float*)d_in[12];
  const float* D_skip    = (const float*)d_in[13];
  const float* out_proj_w= (const float*)d_in[14];
  const float* Wout      = (const float*)d_in[15];
  const float* bout      = (const float*)d_in[16];
  float* out = (float*)d_out;
  float* ws = (float*)d_ws;

  // workspace layout (floats), with lifetime-based reuse. peak = 48496640 f = 185 MB
  float* ob   = ws + 0;          // 4194304   (B,L,D)   live: ob-gemm .. xz-gemm
  float* q    = ws + 4194304;    // 4194304   live: q-gemm .. ob-gemm
  float* kv   = ws + 8388608;    // 8388608   live: kv-gemm .. sim
  float* part = ws + 16777216;   // 2097152   live: sim .. softmax
  float* attn = ws + 18874368;   // 262144    live: softmax .. ob-gemm
  float* xz   = ws + 19136512;   // 16777216  live: xz-gemm .. scanC (z half)
  float* xs   = ws + 0;          // 8388608   reuses ob+q, live: conv .. scanC
  float* dbl  = ws + 8388608;    // 786432    reuses kv, live: dbl-gemm .. scanC
  float* dtb  = ws + 9175040;    // 8388608   reuses kv/part, live: dt .. scanC
  float* Pbuf = ws + 35913728;   // 2097152
  float* Hbuf = ws + 38010880;   // 2097152
  float* ybuf = ws + 40108032;   // 8388608
  float* mbuf = ws + 0;          // 4194304   reuses xs, live: out_proj .. final
  (void)in_sizes; (void)n_in; (void)out_size; (void)ws_size;

  const int M = B_ * L_;
  // q = x @ Wq
  gemm_rrr<<<dim3(D_/64, M/64, 1), 256, 0, stream>>>(x, D_, 0, Wq, D_, 0, q, D_, 0, nullptr, M, D_, D_);
  // kv = context @ Wkv
  gemm_rrr<<<dim3(2*D_/64, M/64, 1), 256, 0, stream>>>(context, D_, 0, Wkv, 2*D_, 0, kv, 2*D_, 0, nullptr, M, 2*D_, D_);
  // sim partials (split-K over L)
  sim_k<<<dim3(4, 4, B_*KS_), 256, 0, stream>>>(kv, part);
  // attn = softmax(SCALE * sum partials)
  softmax_k<<<dim3(B_*D_), 256, 0, stream>>>(part, attn);
  // ob = q @ attn   (batched)
  gemm_rrr<<<dim3(D_/64, L_/64, B_), 256, 0, stream>>>(q, D_, (long)L_*D_, attn, D_, (long)D_*D_, ob, D_, (long)L_*D_, nullptr, L_, D_, D_);
  // hn = LayerNorm(2*ob) in-place
  ln_k<<<dim3(M), 256, 0, stream>>>(ob, ln_w, ln_b);
  // xz = hn @ in_proj_w
  gemm_rrr<<<dim3(2*DI_/64, M/64, 1), 256, 0, stream>>>(ob, D_, 0, in_proj_w, 2*DI_, 0, xz, 2*DI_, 0, nullptr, M, 2*DI_, D_);
  // xs = silu(depthwise_conv(xi) + conv_b)
  conv_silu_k<<<dim3(M), 512, 0, stream>>>(xz, conv_w, conv_b, xs);
  // dbl = xs @ x_proj_w   (N=48, guarded)
  gemm_rrr<<<dim3(1, M/64, 1), 256, 0, stream>>>(xs, DI_, 0, x_proj_w, 48, 0, dbl, 48, 0, nullptr, M, 48, DI_);
  // dt = softplus(dt_r @ dt_proj_w + dt_proj_b)
  dt_k<<<dim3(M), 512, 0, stream>>>(dbl, dt_proj_w, dt_proj_b, dtb);
  // chunked selective scan
  scanA_k<<<dim3(B_*NC_), 512, 0, stream>>>(dtb, xs, dbl, A_log, Pbuf, Hbuf);
  scanB_k<<<dim3(512), 256, 0, stream>>>(Pbuf, Hbuf);
  scanC_k<<<dim3(B_*NC_), 512, 0, stream>>>(dtb, xs, dbl, xz, A_log, D_skip, Hbuf, ybuf);
  // m = y @ out_proj_w
  gemm_rrr<<<dim3(D_/64, M/64, 1), 256, 0, stream>>>(ybuf, DI_, 0, out_proj_w, D_, 0, mbuf, D_, 0, nullptr, M, D_, DI_);
  // out = m @ Wout + bout
  gemm_rrr<<<dim3(D_/64, M/64, 1), 256, 0, stream>>>(mbuf, D_, 0, Wout, D_, 0, out, D_, 0, bout, M, D_, D_);
}